// Round 2
// baseline (519.463 us; speedup 1.0000x reference)
//
#include <hip/hip_runtime.h>

#define D_NODE  128
#define N_BASIS 9
#define D_EDGE  128

#define BLOCK_C 256
#define TPT     4                      // triples per thread
#define CHUNK   (BLOCK_C * TPT)        // 1024 triples per block
#define SEG_CAP 512                    // LDS segment-range capacity

__device__ __forceinline__ float fast_sigmoid(float x) {
    return __builtin_amdgcn_rcpf(1.0f + __expf(-x));
}

// Kernel A: atoms[a][b] = sigmoid(node_feat[a,:] @ W_atom[:,b] + b_atom[b])
__global__ __launch_bounds__(256) void atoms_kernel(
    const float* __restrict__ node_feat,
    const float* __restrict__ W_atom,
    const float* __restrict__ b_atom,
    float* __restrict__ atoms, int n_atoms)
{
    __shared__ float sW[D_NODE * N_BASIS];
    for (int t = threadIdx.x; t < D_NODE * N_BASIS; t += 256)
        sW[t] = W_atom[t];
    __syncthreads();
    int idx = blockIdx.x * 256 + threadIdx.x;
    int total = n_atoms * N_BASIS;
    if (idx >= total) return;
    int a = idx / N_BASIS;
    int b = idx - a * N_BASIS;
    const float* row = node_feat + a * D_NODE;
    float acc = b_atom[b];
#pragma unroll 8
    for (int i = 0; i < D_NODE; ++i)
        acc += row[i] * sW[i * N_BASIS + b];
    atoms[idx] = fast_sigmoid(acc);
}

// Kernel C: streaming segmented reduction over sorted triples.
// Each block: 1024 contiguous triples, LDS accumulation over the block's
// segment range, boundary segments flushed with global f32 atomics,
// interior segments (fully owned, by sortedness) with plain stores.
__global__ __launch_bounds__(BLOCK_C) void triple_kernel(
    const float* __restrict__ three_basis,
    const float* __restrict__ atoms,
    const int*   __restrict__ graph_dst,
    const int*   __restrict__ lg_dst,
    const int*   __restrict__ seg,
    float* __restrict__ new_bonds,
    int n_triples)
{
    __shared__ float lacc[SEG_CAP * N_BASIS];
    __shared__ int sh_first, sh_last;

    const int tid = threadIdx.x;
    const int chunk_start = blockIdx.x * CHUNK;
    const int t0 = chunk_start + tid * TPT;

    if (tid == 0) sh_first = seg[chunk_start];
    if (tid == BLOCK_C - 1) {
        int last = chunk_start + CHUNK;
        if (last > n_triples) last = n_triples;
        sh_last = seg[last - 1];
    }
    for (int i = tid; i < SEG_CAP * N_BASIS; i += BLOCK_C)
        lacc[i] = 0.0f;
    __syncthreads();

    const int seg_first = sh_first;
    const int range = sh_last - seg_first + 1;
    const bool use_lds = (range <= SEG_CAP);

    if (t0 < n_triples) {
        const int nt = min(TPT, n_triples - t0);

        float tbv[TPT * N_BASIS];
        int sgs[TPT];
        int lds_idx[TPT];

        if (nt == TPT) {
            // 4 triples * 9 floats = 144 B = 9 aligned float4 loads
            const float4* tb4 = (const float4*)(three_basis + (size_t)t0 * N_BASIS);
#pragma unroll
            for (int q = 0; q < 9; ++q)
                *(float4*)&tbv[q * 4] = tb4[q];
            int4 sg = *(const int4*)(seg + t0);
            sgs[0] = sg.x; sgs[1] = sg.y; sgs[2] = sg.z; sgs[3] = sg.w;
            int4 ld = *(const int4*)(lg_dst + t0);
            lds_idx[0] = ld.x; lds_idx[1] = ld.y; lds_idx[2] = ld.z; lds_idx[3] = ld.w;
        } else {
            for (int i = 0; i < nt; ++i) {
                sgs[i] = seg[t0 + i];
                lds_idx[i] = lg_dst[t0 + i];
                for (int k = 0; k < N_BASIS; ++k)
                    tbv[i * N_BASIS + k] = three_basis[(size_t)(t0 + i) * N_BASIS + k];
            }
        }

        float sum[N_BASIS];
        int cur = sgs[0];
#pragma unroll
        for (int k = 0; k < N_BASIS; ++k) sum[k] = 0.0f;

#pragma unroll
        for (int i = 0; i < TPT; ++i) {
            if (i >= nt) break;
            if (sgs[i] != cur) {
                // flush current run
                if (use_lds) {
                    float* dst = lacc + (cur - seg_first) * N_BASIS;
#pragma unroll
                    for (int k = 0; k < N_BASIS; ++k) unsafeAtomicAdd(&dst[k], sum[k]);
                } else {
                    float* dst = new_bonds + (size_t)cur * N_BASIS;
#pragma unroll
                    for (int k = 0; k < N_BASIS; ++k) unsafeAtomicAdd(&dst[k], sum[k]);
                }
                cur = sgs[i];
#pragma unroll
                for (int k = 0; k < N_BASIS; ++k) sum[k] = 0.0f;
            }
            int atom = graph_dst[lds_idx[i]];
            const float* arow = atoms + atom * N_BASIS;
#pragma unroll
            for (int k = 0; k < N_BASIS; ++k)
                sum[k] += tbv[i * N_BASIS + k] * arow[k];
        }
        // final flush
        if (use_lds) {
            float* dst = lacc + (cur - seg_first) * N_BASIS;
#pragma unroll
            for (int k = 0; k < N_BASIS; ++k) unsafeAtomicAdd(&dst[k], sum[k]);
        } else {
            float* dst = new_bonds + (size_t)cur * N_BASIS;
#pragma unroll
            for (int k = 0; k < N_BASIS; ++k) unsafeAtomicAdd(&dst[k], sum[k]);
        }
    }

    __syncthreads();

    if (use_lds) {
        int total = range * N_BASIS;
        for (int idx = tid; idx < total; idx += BLOCK_C) {
            int r = idx / N_BASIS;
            int k = idx - r * N_BASIS;
            float v = lacc[idx];
            int s = seg_first + r;
            if (r == 0 || r == range - 1) {
                if (v != 0.0f)
                    unsafeAtomicAdd(&new_bonds[(size_t)s * N_BASIS + k], v);
            } else {
                // interior segment: fully owned by this block (sorted ids)
                new_bonds[(size_t)s * N_BASIS + k] = v;
            }
        }
    }
}

// Kernel D: per-edge gated MLP 9 -> 128 + residual. 32 threads/edge,
// 4 channels/thread, float4 everywhere on the 128-wide arrays.
__global__ __launch_bounds__(256) void mlp_kernel(
    const float* __restrict__ edge_feat,
    const float* __restrict__ new_bonds,
    const float* __restrict__ W_gate, const float* __restrict__ b_gate,
    const float* __restrict__ W_sig,  const float* __restrict__ b_sig,
    float* __restrict__ out, int n_edges)
{
    const int tid = threadIdx.x;
    const int grp = tid >> 5;          // 8 edges per block
    const int c   = (tid & 31) * 4;    // channel base
    const int e   = blockIdx.x * 8 + grp;
    if (e >= n_edges) return;

    float nb[N_BASIS];
    const float* nbr = new_bonds + (size_t)e * N_BASIS;
#pragma unroll
    for (int k = 0; k < N_BASIS; ++k) nb[k] = nbr[k];

    float4 g = *(const float4*)(b_gate + c);
    float4 s = *(const float4*)(b_sig + c);
#pragma unroll
    for (int k = 0; k < N_BASIS; ++k) {
        float4 wg = *(const float4*)(W_gate + k * D_EDGE + c);
        float4 ws = *(const float4*)(W_sig  + k * D_EDGE + c);
        g.x += nb[k] * wg.x; g.y += nb[k] * wg.y;
        g.z += nb[k] * wg.z; g.w += nb[k] * wg.w;
        s.x += nb[k] * ws.x; s.y += nb[k] * ws.y;
        s.z += nb[k] * ws.z; s.w += nb[k] * ws.w;
    }
    float4 ef = *(const float4*)(edge_feat + (size_t)e * D_EDGE + c);
    float4 o;
    o.x = ef.x + g.x * fast_sigmoid(g.x) * fast_sigmoid(s.x);
    o.y = ef.y + g.y * fast_sigmoid(g.y) * fast_sigmoid(s.y);
    o.z = ef.z + g.z * fast_sigmoid(g.z) * fast_sigmoid(s.z);
    o.w = ef.w + g.w * fast_sigmoid(g.w) * fast_sigmoid(s.w);
    *(float4*)(out + (size_t)e * D_EDGE + c) = o;
}

extern "C" void kernel_launch(void* const* d_in, const int* in_sizes, int n_in,
                              void* d_out, int out_size, void* d_ws, size_t ws_size,
                              hipStream_t stream) {
    const float* node_feat   = (const float*)d_in[0];
    const float* edge_feat   = (const float*)d_in[1];
    const float* three_basis = (const float*)d_in[2];
    // d_in[3] three_cutoff: dead code in reference
    const float* W_atom      = (const float*)d_in[4];
    const float* b_atom      = (const float*)d_in[5];
    const float* W_gate      = (const float*)d_in[6];
    const float* b_gate      = (const float*)d_in[7];
    const float* W_sig       = (const float*)d_in[8];
    const float* b_sig       = (const float*)d_in[9];
    const int*   graph_dst   = (const int*)d_in[10];
    // d_in[11] lg_src: dead code in reference
    const int*   lg_dst      = (const int*)d_in[12];
    const int*   seg         = (const int*)d_in[13];

    int n_atoms   = in_sizes[0] / D_NODE;
    int n_edges   = in_sizes[1] / D_EDGE;
    int n_triples = in_sizes[2] / N_BASIS;

    // ws layout: atoms [n_atoms*9 f32] | new_bonds [n_edges*9 f32]
    float* atoms = (float*)d_ws;
    size_t atoms_bytes = ((size_t)n_atoms * N_BASIS * sizeof(float) + 255) & ~(size_t)255;
    float* new_bonds = (float*)((char*)d_ws + atoms_bytes);
    size_t nb_bytes = (size_t)n_edges * N_BASIS * sizeof(float);

    hipMemsetAsync(new_bonds, 0, nb_bytes, stream);

    atoms_kernel<<<(n_atoms * N_BASIS + 255) / 256, 256, 0, stream>>>(
        node_feat, W_atom, b_atom, atoms, n_atoms);

    triple_kernel<<<(n_triples + CHUNK - 1) / CHUNK, BLOCK_C, 0, stream>>>(
        three_basis, atoms, graph_dst, lg_dst, seg, new_bonds, n_triples);

    mlp_kernel<<<(n_edges + 7) / 8, 256, 0, stream>>>(
        edge_feat, new_bonds, W_gate, b_gate, W_sig, b_sig, out_size ? (float*)d_out : (float*)d_out, n_edges);
}

// Round 3
// 461.902 us; speedup vs baseline: 1.1246x; 1.1246x over previous
//
#include <hip/hip_runtime.h>

#define D_NODE   128
#define N_BASIS  9
#define A_STRIDE 12                    // padded atoms row stride (48 B, float4-aligned)
#define D_EDGE   128

#define BLOCK_C 256
#define TPT     4                      // triples per thread
#define CHUNK   (BLOCK_C * TPT)        // 1024 triples per block
#define SEG_CAP 512                    // LDS segment-range capacity

__device__ __forceinline__ float fast_sigmoid(float x) {
    return __builtin_amdgcn_rcpf(1.0f + __expf(-x));
}

// Kernel A: atoms[a][b] = sigmoid(node_feat[a,:] @ W_atom[:,b] + b_atom[b]),
// written with row stride A_STRIDE (pad elements never read).
__global__ __launch_bounds__(256) void atoms_kernel(
    const float* __restrict__ node_feat,
    const float* __restrict__ W_atom,
    const float* __restrict__ b_atom,
    float* __restrict__ atoms, int n_atoms)
{
    __shared__ float sW[D_NODE * N_BASIS];
    for (int t = threadIdx.x; t < D_NODE * N_BASIS; t += 256)
        sW[t] = W_atom[t];
    __syncthreads();
    int idx = blockIdx.x * 256 + threadIdx.x;
    int total = n_atoms * N_BASIS;
    if (idx >= total) return;
    int a = idx / N_BASIS;
    int b = idx - a * N_BASIS;
    const float* row = node_feat + a * D_NODE;
    float acc = b_atom[b];
#pragma unroll 8
    for (int i = 0; i < D_NODE; ++i)
        acc += row[i] * sW[i * N_BASIS + b];
    atoms[a * A_STRIDE + b] = fast_sigmoid(acc);
}

#define FLUSH_RUN()                                                          \
    do {                                                                     \
        if (use_lds) {                                                       \
            float* dst_ = lacc + (cur - seg_first) * N_BASIS;                \
            _Pragma("unroll")                                                \
            for (int k_ = 0; k_ < N_BASIS; ++k_)                             \
                atomicAdd(&dst_[k_], sum[k_]);                               \
        } else {                                                             \
            float* dst_ = new_bonds + (size_t)cur * N_BASIS;                 \
            _Pragma("unroll")                                                \
            for (int k_ = 0; k_ < N_BASIS; ++k_)                             \
                unsafeAtomicAdd(&dst_[k_], sum[k_]);                         \
        }                                                                    \
    } while (0)

// Kernel C: streaming segmented reduction over sorted triples.
// 1024 contiguous triples per block; LDS accumulation over the block's
// segment range; boundary segments flushed with global f32 atomics,
// interior segments (fully owned, by sortedness) with plain stores.
// NO dynamically-indexed private arrays anywhere (R2's scratch-spill bug).
__global__ __launch_bounds__(BLOCK_C) void triple_kernel(
    const float* __restrict__ three_basis,
    const float* __restrict__ atoms,
    const int*   __restrict__ graph_dst,
    const int*   __restrict__ lg_dst,
    const int*   __restrict__ seg,
    float* __restrict__ new_bonds,
    int n_triples)
{
    __shared__ float lacc[SEG_CAP * N_BASIS];   // 18432 B
    __shared__ int sh_first, sh_last;

    const int tid = threadIdx.x;
    const int chunk_start = blockIdx.x * CHUNK;
    const int t0 = chunk_start + tid * TPT;

    if (tid == 0) sh_first = seg[chunk_start];
    if (tid == BLOCK_C - 1) {
        int last = chunk_start + CHUNK;
        if (last > n_triples) last = n_triples;
        sh_last = seg[last - 1];
    }
    for (int i = tid; i < SEG_CAP * N_BASIS; i += BLOCK_C)
        lacc[i] = 0.0f;
    __syncthreads();

    const int seg_first = sh_first;
    const int range = sh_last - seg_first + 1;
    const bool use_lds = (range <= SEG_CAP);

    if (t0 + TPT <= n_triples) {
        // ---- fast path: everything compile-time indexed ----
        float tb[TPT * N_BASIS];
        const float4* tb4 = (const float4*)(three_basis + (size_t)t0 * N_BASIS);
#pragma unroll
        for (int q = 0; q < 9; ++q)
            *(float4*)&tb[q * 4] = tb4[q];      // constant index after unroll

        const int4 sg4 = *(const int4*)(seg + t0);
        const int4 ld4 = *(const int4*)(lg_dst + t0);
        int sgs[TPT]  = { sg4.x, sg4.y, sg4.z, sg4.w };
        int atomi[TPT];
        atomi[0] = graph_dst[ld4.x];
        atomi[1] = graph_dst[ld4.y];
        atomi[2] = graph_dst[ld4.z];
        atomi[3] = graph_dst[ld4.w];

        float sum[N_BASIS];
        int cur = sgs[0];
#pragma unroll
        for (int k = 0; k < N_BASIS; ++k) sum[k] = 0.0f;

#pragma unroll
        for (int i = 0; i < TPT; ++i) {
            if (sgs[i] != cur) {
                FLUSH_RUN();
                cur = sgs[i];
#pragma unroll
                for (int k = 0; k < N_BASIS; ++k) sum[k] = 0.0f;
            }
            const float4* ap = (const float4*)(atoms + (size_t)atomi[i] * A_STRIDE);
            float4 a0 = ap[0];
            float4 a1 = ap[1];
            float  a8 = ((const float*)ap)[8];
            sum[0] += tb[i * N_BASIS + 0] * a0.x;
            sum[1] += tb[i * N_BASIS + 1] * a0.y;
            sum[2] += tb[i * N_BASIS + 2] * a0.z;
            sum[3] += tb[i * N_BASIS + 3] * a0.w;
            sum[4] += tb[i * N_BASIS + 4] * a1.x;
            sum[5] += tb[i * N_BASIS + 5] * a1.y;
            sum[6] += tb[i * N_BASIS + 6] * a1.z;
            sum[7] += tb[i * N_BASIS + 7] * a1.w;
            sum[8] += tb[i * N_BASIS + 8] * a8;
        }
        FLUSH_RUN();
    } else if (t0 < n_triples) {
        // ---- array-free tail path (unused when n_triples % 4 == 0) ----
        for (int t = t0; t < n_triples; ++t) {
            int cur = seg[t];
            int atom = graph_dst[lg_dst[t]];
            const float* tbr = three_basis + (size_t)t * N_BASIS;
            const float* ar  = atoms + (size_t)atom * A_STRIDE;
            float sum[N_BASIS];
#pragma unroll
            for (int k = 0; k < N_BASIS; ++k) sum[k] = tbr[k] * ar[k];
            FLUSH_RUN();
        }
    }

    __syncthreads();

    if (use_lds) {
        int total = range * N_BASIS;
        for (int idx = tid; idx < total; idx += BLOCK_C) {
            int r = idx / N_BASIS;
            int k = idx - r * N_BASIS;
            float v = lacc[idx];
            int s = seg_first + r;
            if (r == 0 || r == range - 1) {
                if (v != 0.0f)
                    unsafeAtomicAdd(&new_bonds[(size_t)s * N_BASIS + k], v);
            } else {
                new_bonds[(size_t)s * N_BASIS + k] = v;   // fully owned
            }
        }
    }
}

// Kernel D: per-edge gated MLP 9 -> 128 + residual. 32 threads/edge,
// 4 channels/thread, float4 on all 128-wide arrays.
__global__ __launch_bounds__(256) void mlp_kernel(
    const float* __restrict__ edge_feat,
    const float* __restrict__ new_bonds,
    const float* __restrict__ W_gate, const float* __restrict__ b_gate,
    const float* __restrict__ W_sig,  const float* __restrict__ b_sig,
    float* __restrict__ out, int n_edges)
{
    const int tid = threadIdx.x;
    const int grp = tid >> 5;          // 8 edges per block
    const int c   = (tid & 31) * 4;    // channel base
    const int e   = blockIdx.x * 8 + grp;
    if (e >= n_edges) return;

    float nb[N_BASIS];
    const float* nbr = new_bonds + (size_t)e * N_BASIS;
#pragma unroll
    for (int k = 0; k < N_BASIS; ++k) nb[k] = nbr[k];

    float4 g = *(const float4*)(b_gate + c);
    float4 s = *(const float4*)(b_sig + c);
#pragma unroll
    for (int k = 0; k < N_BASIS; ++k) {
        float4 wg = *(const float4*)(W_gate + k * D_EDGE + c);
        float4 ws = *(const float4*)(W_sig  + k * D_EDGE + c);
        g.x += nb[k] * wg.x; g.y += nb[k] * wg.y;
        g.z += nb[k] * wg.z; g.w += nb[k] * wg.w;
        s.x += nb[k] * ws.x; s.y += nb[k] * ws.y;
        s.z += nb[k] * ws.z; s.w += nb[k] * ws.w;
    }
    float4 ef = *(const float4*)(edge_feat + (size_t)e * D_EDGE + c);
    float4 o;
    o.x = ef.x + g.x * fast_sigmoid(g.x) * fast_sigmoid(s.x);
    o.y = ef.y + g.y * fast_sigmoid(g.y) * fast_sigmoid(s.y);
    o.z = ef.z + g.z * fast_sigmoid(g.z) * fast_sigmoid(s.z);
    o.w = ef.w + g.w * fast_sigmoid(g.w) * fast_sigmoid(s.w);
    *(float4*)(out + (size_t)e * D_EDGE + c) = o;
}

extern "C" void kernel_launch(void* const* d_in, const int* in_sizes, int n_in,
                              void* d_out, int out_size, void* d_ws, size_t ws_size,
                              hipStream_t stream) {
    const float* node_feat   = (const float*)d_in[0];
    const float* edge_feat   = (const float*)d_in[1];
    const float* three_basis = (const float*)d_in[2];
    // d_in[3] three_cutoff: dead code in reference
    const float* W_atom      = (const float*)d_in[4];
    const float* b_atom      = (const float*)d_in[5];
    const float* W_gate      = (const float*)d_in[6];
    const float* b_gate      = (const float*)d_in[7];
    const float* W_sig       = (const float*)d_in[8];
    const float* b_sig       = (const float*)d_in[9];
    const int*   graph_dst   = (const int*)d_in[10];
    // d_in[11] lg_src: dead code in reference
    const int*   lg_dst      = (const int*)d_in[12];
    const int*   seg         = (const int*)d_in[13];

    int n_atoms   = in_sizes[0] / D_NODE;
    int n_edges   = in_sizes[1] / D_EDGE;
    int n_triples = in_sizes[2] / N_BASIS;

    // ws layout: atoms [n_atoms*12 f32, padded] | new_bonds [n_edges*9 f32]
    float* atoms = (float*)d_ws;
    size_t atoms_bytes = ((size_t)n_atoms * A_STRIDE * sizeof(float) + 255) & ~(size_t)255;
    float* new_bonds = (float*)((char*)d_ws + atoms_bytes);
    size_t nb_bytes = (size_t)n_edges * N_BASIS * sizeof(float);

    hipMemsetAsync(new_bonds, 0, nb_bytes, stream);

    atoms_kernel<<<(n_atoms * N_BASIS + 255) / 256, 256, 0, stream>>>(
        node_feat, W_atom, b_atom, atoms, n_atoms);

    triple_kernel<<<(n_triples + CHUNK - 1) / CHUNK, BLOCK_C, 0, stream>>>(
        three_basis, atoms, graph_dst, lg_dst, seg, new_bonds, n_triples);

    mlp_kernel<<<(n_edges + 7) / 8, 256, 0, stream>>>(
        edge_feat, new_bonds, W_gate, b_gate, W_sig, b_sig, (float*)d_out, n_edges);
}